// Round 12
// baseline (856.473 us; speedup 1.0000x reference)
//
#include <hip/hip_runtime.h>
#include <stdint.h>

#define BATCH 8
#define C 128
#define TPB 256
#define GEMM_BLOCKS 1024
#define TILE_R 128
#define KC 8
#define NCHUNK (C / KC)   // 16
#define HGRID 2048

typedef float v2f __attribute__((ext_vector_type(2)));
typedef float v4f __attribute__((ext_vector_type(4)));

// order-preserving float -> uint key (monotone: a<b  <=>  key(a)<key(b))
__device__ __forceinline__ unsigned f2key(float f){
  unsigned b = __float_as_uint(f);
  return (b & 0x80000000u) ? ~b : (b | 0x80000000u);
}

// ---------------------------------------------------------------------------
// Outer-product GEMM with PACKED f32 FMAs (v_pk_fma_f32 via llvm.fma.v2f32).
// 7 flat rounds (443-470us, VALU 45-48%, occupancy-insensitive) localize the
// wall at the scalar v_fma_f32 issue port: 59 TF measured = 75% of the 78.6TF
// plain-FMA SIMD-32 ceiling. The 157.3 TF spec rate requires packed math.
// acc paired over ROW-pairs: acc2[jj][i] = (acc[2jj][i], acc[2jj+1][i]);
// A-frag pairs are natural sub-pairs of the b128 LDS reads (zero shuffles);
// B scalar is splat per column (amortized over 4 pk-FMAs). Each lane-FMA has
// IDENTICAL operands and k-order as rounds 1-11 -> bit-identical h and pred.
// B (W1, 64KB, L2-hot) from global, pipelined 2-deep over ABSOLUTE k (W1 is
// tile-invariant, so the B pipeline crosses chunk barriers freely).
// A in LDS [2][8][128] dbuf, 1-deep register pipeline (r9).
// ---------------------------------------------------------------------------
__global__ __launch_bounds__(TPB, 1) void k_gemm(
    const float* __restrict__ fea, const float* __restrict__ W1,
    const float* __restrict__ b1, const float* __restrict__ W2,
    const float* __restrict__ b2, const int* __restrict__ vox,
    float* __restrict__ out, float* __restrict__ pred,
    unsigned* __restrict__ segkey, int N)
{
  __shared__ float sA[2][KC][TILE_R];   // 8KB, transposed fea tile, dbuf

  const int tid  = threadIdx.x;
  const int lane = tid & 63;
  const int wid  = tid >> 6;              // 0..3
  const int wr   = wid >> 1;              // 0..1 row-group
  const int wc   = wid & 1;               // 0..1 col-group
  const int rowoff = wr * 64 + (lane >> 3) * 8;   // in-tile row base (0..120)
  const int coloff = wc * 64 + (lane & 7) * 8;    // col base (0..120)

  float b1v[8];
  #pragma unroll
  for (int i = 0; i < 8; ++i) b1v[i] = b1[coloff + i];
  const double b2d = (double)b2[0];

  const float* wcol = W1 + coloff;        // B(k) = wcol[k*C .. k*C+7]

  const int nTiles = N / TILE_R;          // 6250
  const int srow = tid >> 1;              // staging: row in tile (0..127)
  const int skq  = tid & 1;               // which float4 of the 8-k chunk

  for (int tile = blockIdx.x; tile < nTiles; tile += GEMM_BLOCKS) {
    const size_t trow = (size_t)tile * TILE_R;

    // ---- prologue: stage chunk 0 + prime B pipeline (k=0,1) ----
    float4 st = *(const float4*)(fea + (trow + srow) * C + skq * 4);
    {
      float* d = &sA[0][skq * 4][srow];
      d[0] = st.x; d[TILE_R] = st.y; d[2 * TILE_R] = st.z; d[3 * TILE_R] = st.w;
    }
    v4f bAc = *reinterpret_cast<const v4f*>(wcol);
    v4f bBc = *reinterpret_cast<const v4f*>(wcol + 4);
    v4f bAn = *reinterpret_cast<const v4f*>(wcol + C);
    v4f bBn = *reinterpret_cast<const v4f*>(wcol + C + 4);
    __syncthreads();

    v2f acc2[4][8];   // row-pairs x 8 cols
    #pragma unroll
    for (int jj = 0; jj < 4; ++jj)
      #pragma unroll
      for (int i = 0; i < 8; ++i) acc2[jj][i] = (v2f){b1v[i], b1v[i]};

    // ---- k-chunk loop: one barrier per chunk ----
    #pragma unroll 1
    for (int kb = 0; kb < NCHUNK; ++kb) {
      if (kb + 1 < NCHUNK)   // global fea prefetch for next chunk
        st = *(const float4*)(fea + (trow + srow) * C + (kb + 1) * KC + skq * 4);

      const float* sAc = &sA[kb & 1][0][0];

      // A(k=0) fragments for this chunk
      v4f a0 = *reinterpret_cast<const v4f*>(sAc + rowoff);
      v4f a1 = *reinterpret_cast<const v4f*>(sAc + rowoff + 4);

      #pragma unroll
      for (int k = 0; k < KC; ++k) {
        const int kko = kb * KC + k;
        v4f bA2, bB2;
        if (kko + 2 < C) {   // issue B(k+2): 2-deep VMEM pipeline
          bA2 = *reinterpret_cast<const v4f*>(wcol + (size_t)(kko + 2) * C);
          bB2 = *reinterpret_cast<const v4f*>(wcol + (size_t)(kko + 2) * C + 4);
        }
        v4f na0, na1;
        if (k + 1 < KC) {    // issue A(k+1): 1-deep LDS pipeline
          na0 = *reinterpret_cast<const v4f*>(sAc + (k + 1) * TILE_R + rowoff);
          na1 = *reinterpret_cast<const v4f*>(sAc + (k + 1) * TILE_R + rowoff + 4);
        }

        const v2f af2[4] = { a0.xy, a0.zw, a1.xy, a1.zw };
        const float bf[8] = {bAc.x, bAc.y, bAc.z, bAc.w, bBc.x, bBc.y, bBc.z, bBc.w};
        #pragma unroll
        for (int i = 0; i < 8; ++i) {
          const v2f bs = {bf[i], bf[i]};
          #pragma unroll
          for (int jj = 0; jj < 4; ++jj)
            acc2[jj][i] = __builtin_elementwise_fma(af2[jj], bs, acc2[jj][i]);
        }

        if (k + 1 < KC) { a0 = na0; a1 = na1; }
        bAc = bAn; bBc = bBn;
        if (kko + 2 < C) { bAn = bA2; bBn = bB2; }
      }

      if (kb + 1 < NCHUNK) {
        float* d = &sA[(kb + 1) & 1][skq * 4][srow];
        d[0] = st.x; d[TILE_R] = st.y; d[2 * TILE_R] = st.z; d[3 * TILE_R] = st.w;
      }
      __syncthreads();
    }

    // ---- epilogue: relu + store h, f64 pred, segment max ----
    float w2f[8];
    #pragma unroll
    for (int i = 0; i < 8; ++i) w2f[i] = W2[coloff + i];
    double pdv[8];
    #pragma unroll
    for (int j = 0; j < 8; ++j) {
      float hv[8];
      #pragma unroll
      for (int i = 0; i < 8; ++i) hv[i] = fmaxf(acc2[j >> 1][i][j & 1], 0.f);
      const size_t row = trow + rowoff + j;
      *(float4*)(out + row * C + coloff)     = make_float4(hv[0], hv[1], hv[2], hv[3]);
      *(float4*)(out + row * C + coloff + 4) = make_float4(hv[4], hv[5], hv[6], hv[7]);
      double pd = 0.0;
      #pragma unroll
      for (int i = 0; i < 8; ++i) pd += (double)hv[i] * (double)w2f[i];
      pdv[j] = pd;
    }
    #pragma unroll
    for (int j = 0; j < 8; ++j) {   // reduce over the 8-lane col group
      double pd = pdv[j];
      pd += __shfl_xor(pd, 1, 64);
      pd += __shfl_xor(pd, 2, 64);
      pd += __shfl_xor(pd, 4, 64);
      pdv[j] = pd;
    }
    double* sPred = (double*)&sA[0][0][0];   // 256 doubles (2KB) overlay
    if ((lane & 7) == 0) {
      #pragma unroll
      for (int j = 0; j < 8; ++j) sPred[wc * TILE_R + rowoff + j] = pdv[j];
    }
    __syncthreads();
    if (tid < TILE_R) {
      const double s = sPred[tid] + sPred[TILE_R + tid] + b2d;
      const float pv = (float)s;
      const size_t row = trow + tid;
      pred[row] = pv;
      atomicMax(&segkey[vox[row]], f2key(pv));
    }
    __syncthreads();   // sPred consumed before next tile's staging write
  }
}

// ---------------------------------------------------------------------------
// Pass A: valkey + per-row histogram of byte1 (vk>>24), LDS-accumulated.
// ---------------------------------------------------------------------------
__global__ __launch_bounds__(256) void k_histA(
    const float* __restrict__ pred, const int* __restrict__ vox,
    const unsigned* __restrict__ segkey, unsigned* __restrict__ valkey,
    unsigned* __restrict__ histA, int N, int M)
{
  __shared__ unsigned lh[BATCH * 256];
  for (int b = threadIdx.x; b < BATCH * 256; b += 256) lh[b] = 0;
  __syncthreads();
  const int stride = gridDim.x * 256;
  for (int i = blockIdx.x * 256 + threadIdx.x; i < N; i += stride) {
    unsigned kk = f2key(pred[i]);
    unsigned vk = (kk == segkey[vox[i]]) ? 0xFFFFFFFFu : kk;
    valkey[i] = vk;
    atomicAdd(&lh[(i / M) * 256 + (vk >> 24)], 1u);
  }
  __syncthreads();
  for (int b = threadIdx.x; b < BATCH * 256; b += 256)
    if (lh[b]) atomicAdd(&histA[b], lh[b]);
}

// Pass B: byte2 among elements whose byte1 matches the selected bin.
__global__ __launch_bounds__(256) void k_histB(
    const unsigned* __restrict__ valkey, const unsigned* __restrict__ sel,
    unsigned* __restrict__ histB, int N, int M)
{
  __shared__ unsigned lh[BATCH * 256];
  for (int b = threadIdx.x; b < BATCH * 256; b += 256) lh[b] = 0;
  __syncthreads();
  const int stride = gridDim.x * 256;
  for (int i = blockIdx.x * 256 + threadIdx.x; i < N; i += stride) {
    unsigned vk = valkey[i];
    int row = i / M;
    if ((vk >> 24) == sel[row * 4 + 0])
      atomicAdd(&lh[row * 256 + ((vk >> 16) & 255u)], 1u);
  }
  __syncthreads();
  for (int b = threadIdx.x; b < BATCH * 256; b += 256)
    if (lh[b]) atomicAdd(&histB[b], lh[b]);
}

// Pass C: low 16 bits among elements whose top16 matches (few -> global ok).
__global__ __launch_bounds__(256) void k_histC(
    const unsigned* __restrict__ valkey, const unsigned* __restrict__ sel,
    unsigned* __restrict__ histC, int N, int M)
{
  const int stride = gridDim.x * 256;
  for (int i = blockIdx.x * 256 + threadIdx.x; i < N; i += stride) {
    unsigned vk = valkey[i];
    int row = i / M;
    if ((vk >> 16) == sel[row * 4 + 0])
      atomicAdd(&histC[(size_t)row * 65536 + (vk & 0xFFFFu)], 1u);
  }
}

// scans: find smallest bin with cumulative count >= k (k = M - target_num)
__global__ void k_scan256(const unsigned* __restrict__ hist,
                          unsigned* __restrict__ sel,
                          const int* __restrict__ tnum, int M, int pass)
{
  const int row = blockIdx.x;
  __shared__ unsigned h[256];
  h[threadIdx.x] = hist[row * 256 + threadIdx.x];
  __syncthreads();
  if (threadIdx.x == 0) {
    const unsigned k = (unsigned)(M - tnum[0]);
    unsigned cum = (pass == 0) ? 0u : sel[row * 4 + 1];
    unsigned bin = 255;
    for (int i = 0; i < 256; ++i) {
      if (cum + h[i] >= k) { bin = (unsigned)i; break; }
      cum += h[i];
    }
    if (pass == 0) { sel[row * 4 + 0] = bin; }
    else           { sel[row * 4 + 0] = (sel[row * 4 + 0] << 8) | bin; }
    sel[row * 4 + 1] = cum;
  }
}

__global__ void k_scan64k(const unsigned* __restrict__ hist,
                          unsigned* __restrict__ sel,
                          const int* __restrict__ tnum, int M)
{
  const int row = blockIdx.x;
  const int t = threadIdx.x;  // 256
  const unsigned* h = hist + (size_t)row * 65536;
  __shared__ unsigned part[256];
  const uint4* hv = (const uint4*)(h + t * 256);
  unsigned s = 0;
  for (int i = 0; i < 64; ++i) { uint4 v = hv[i]; s += v.x + v.y + v.z + v.w; }
  part[t] = s;
  __syncthreads();
  if (t == 0) {
    const unsigned k = (unsigned)(M - tnum[0]);
    unsigned cum = sel[row * 4 + 1];
    int seg = 255;
    for (int i = 0; i < 256; ++i) {
      if (cum + part[i] >= k) { seg = i; break; }
      cum += part[i];
    }
    unsigned bin = 0;
    for (int i = 0; i < 256; ++i) {
      unsigned c = h[seg * 256 + i];
      if (cum + c >= k) { bin = (unsigned)(seg * 256 + i); break; }
      cum += c;
    }
    sel[row * 4 + 2] = (sel[row * 4 + 0] << 16) | bin;
  }
}

__global__ void k_scatter(const int* __restrict__ tidx, float* __restrict__ kt, int n)
{
  int i = blockIdx.x * blockDim.x + threadIdx.x;
  if (i < n) kt[tidx[i]] = 1.0f;
}

// zero rows that are not kept.  keep = (valkey > thr) | is_target
__global__ __launch_bounds__(256) void k_final(const unsigned* __restrict__ valkey,
    const float* __restrict__ kt, const unsigned* __restrict__ sel,
    float* __restrict__ out, int N, int M)
{
  const int wid = threadIdx.x >> 6;
  const int lane = threadIdx.x & 63;
  const int nw = gridDim.x * 4;
  for (int r = blockIdx.x * 4 + wid; r < N; r += nw) {
    unsigned vk = valkey[r];
    float kv = kt[r];
    unsigned thr = sel[(r / M) * 4 + 2];
    bool keep = (vk > thr) || (kv != 0.0f);
    if (!keep)
      *(float2*)&out[(size_t)r * C + lane * 2] = make_float2(0.f, 0.f);
  }
}

// ---------------------------------------------------------------------------
extern "C" void kernel_launch(void* const* d_in, const int* in_sizes, int n_in,
                              void* d_out, int out_size, void* d_ws, size_t ws_size,
                              hipStream_t stream)
{
  const float* fea = (const float*)d_in[0];
  const float* W1  = (const float*)d_in[1];
  const float* b1  = (const float*)d_in[2];
  const float* W2  = (const float*)d_in[3];
  const float* b2  = (const float*)d_in[4];
  const int* vox   = (const int*)d_in[5];
  const int* tidx  = (const int*)d_in[6];
  const int* tnum  = (const int*)d_in[7];

  const int N = in_sizes[5];      // 800000
  const int M = N / BATCH;        // 100000
  const int nT = in_sizes[6];     // 400000

  float* out  = (float*)d_out;
  float* pred = out + (size_t)N * C;
  float* kt   = pred + N;

  // workspace layout (zeroed region first, then valkey)
  char* w = (char*)d_ws;
  unsigned* segkey = (unsigned*)(w);                       // 512KB
  unsigned* histA  = (unsigned*)(w + (512u << 10));        // 8KB
  unsigned* histB  = (unsigned*)(w + (520u << 10));        // 8KB
  unsigned* sel    = (unsigned*)(w + (528u << 10));        // 4KB
  unsigned* histC  = (unsigned*)(w + (532u << 10));        // 2MB
  unsigned* valkey = (unsigned*)(w + (532u << 10) + (2u << 20));

  const size_t zbytes = (532u << 10) + (2u << 20);
  hipMemsetAsync(d_ws, 0, zbytes, stream);
  hipMemsetAsync(kt, 0, (size_t)N * sizeof(float), stream);

  k_scatter<<<(nT + 255) / 256, 256, 0, stream>>>(tidx, kt, nT);
  k_gemm<<<GEMM_BLOCKS, TPB, 0, stream>>>(fea, W1, b1, W2, b2, vox,
                                          out, pred, segkey, N);
  k_histA<<<HGRID, 256, 0, stream>>>(pred, vox, segkey, valkey, histA, N, M);
  k_scan256<<<BATCH, 256, 0, stream>>>(histA, sel, tnum, M, 0);
  k_histB<<<HGRID, 256, 0, stream>>>(valkey, sel, histB, N, M);
  k_scan256<<<BATCH, 256, 0, stream>>>(histB, sel, tnum, M, 1);
  k_histC<<<HGRID, 256, 0, stream>>>(valkey, sel, histC, N, M);
  k_scan64k<<<BATCH, 256, 0, stream>>>(histC, sel, tnum, M);
  k_final<<<2048, 256, 0, stream>>>(valkey, kt, sel, out, N, M);
}